// Round 4
// baseline (41236.475 us; speedup 1.0000x reference)
//
#include <hip/hip_runtime.h>
#include <hip/hip_cooperative_groups.h>

namespace cg = cooperative_groups;

// Problem constants (fixed by setup_inputs / reference)
constexpr int   NROWS   = 131072;
constexpr int   KCOLS   = 512;
constexpr int   KP1     = 513;   // + dummy column
constexpr float PA      = 1.0f / 131072.0f;
constexpr float PB_REAL = 0.5f / 512.0f;
constexpr float PB_DUM  = 0.5f;
constexpr float FI      = (float)(1.0 / 1.1); // GAMMA/(GAMMA+EPSILON)
constexpr float STOPERR = 1e-6f;
constexpr int   MAXIT   = 1000;
constexpr float LOG2E   = 1.4426950408889634f;
constexpr float CQ      = 10.0f * LOG2E;      // (1/EPSILON)*log2(e)
constexpr float LN2     = 0.6931471805599453f;

// Cooperative config: 256 blocks x 1024 threads, 1 block/CU, 16 waves/CU,
// VGPR cap 128 (launch_bounds min 4 waves/EU) -> no spills, 4-row unroll.
constexpr int BLOCKS  = 256;
constexpr int THREADS = 1024;
constexpr int WPB     = THREADS / 64;     // 16 waves per block
constexpr int NWAVES  = BLOCKS * WPB;     // 4096 waves
// NROWS / NWAVES = 32 rows per wave, in 8 groups of 4 (unroll)

// Workspace layout (floats). Total ~ 131072 + 4*520 + 256*513 ~ 1.1 MB.
constexpr size_t OFF_A   = 0;                        // [NROWS] scaling a
constexpr int    KPAD    = 520;                      // 16B-aligned b stride
constexpr size_t OFF_B0  = (size_t)NROWS;            // [KPAD]  b ping
constexpr size_t OFF_B1  = OFF_B0 + KPAD;            // [KPAD]  b pong
constexpr size_t OFF_BF  = OFF_B0 + 2 * KPAD;        // [KPAD]  b final
constexpr size_t OFF_EP  = OFF_B0 + 3 * KPAD;        // [KPAD]  per-col diff^2
constexpr size_t OFF_CP  = OFF_B0 + 4 * KPAD;        // [BLOCKS*KP1] col partials

__device__ __forceinline__ float waveReduceSum(float v) {
#pragma unroll
  for (int s = 32; s >= 1; s >>= 1) v += __shfl_xor(v, s);
  return v;
}
__device__ __forceinline__ float waveReduceMax(float v) {
#pragma unroll
  for (int s = 32; s >= 1; s >>= 1) v = fmaxf(v, __shfl_xor(v, s));
  return v;
}

__device__ __forceinline__ float dot8(const float4 a0, const float4 a1,
                                      const float4 b0, const float4 b1) {
  return ((a0.x * b0.x + a0.y * b0.y) + (a0.z * b0.z + a0.w * b0.w))
       + ((a1.x * b1.x + a1.y * b1.y) + (a1.z * b1.z + a1.w * b1.w));
}

__device__ __forceinline__ void cpadd(const float4 a0, const float4 a1,
                                      const float ai, float cp[8]) {
  cp[0] += ai * a0.x;  cp[1] += ai * a0.y;
  cp[2] += ai * a0.z;  cp[3] += ai * a0.w;
  cp[4] += ai * a1.x;  cp[5] += ai * a1.y;
  cp[6] += ai * a1.z;  cp[7] += ai * a1.w;
}

// ---------------------------------------------------------------------------
// Kernel 1: per-row logsumexp + f32 Q precompute (Q -> d_out scratch, 268 MB),
// plus init of b0 = 1/(k+1).
// One wave per row; lane l holds cols [4l..4l+3] and [256+4l..256+4l+3].
// Q stored in natural order: row r = float[512] at qb + r*512.
// ---------------------------------------------------------------------------
__global__ __launch_bounds__(1024) void lse_q_init_kernel(
    const float* __restrict__ logits, float* __restrict__ ws,
    float* __restrict__ qb) {
  const int nw   = (gridDim.x * blockDim.x) >> 6;
  const int gw   = (blockIdx.x * blockDim.x + threadIdx.x) >> 6;
  const int lane = threadIdx.x & 63;

  for (int r = gw; r < NROWS; r += nw) {
    const float4* row4 = reinterpret_cast<const float4*>(logits + (size_t)r * KCOLS);
    float4 x0 = row4[lane];
    float4 x1 = row4[64 + lane];
    float m = fmaxf(fmaxf(fmaxf(x0.x, x0.y), fmaxf(x0.z, x0.w)),
                    fmaxf(fmaxf(x1.x, x1.y), fmaxf(x1.z, x1.w)));
    m = waveReduceMax(m);
    float s = exp2f((x0.x - m) * LOG2E) + exp2f((x0.y - m) * LOG2E)
            + exp2f((x0.z - m) * LOG2E) + exp2f((x0.w - m) * LOG2E)
            + exp2f((x1.x - m) * LOG2E) + exp2f((x1.y - m) * LOG2E)
            + exp2f((x1.z - m) * LOG2E) + exp2f((x1.w - m) * LOG2E);
    s = waveReduceSum(s);
    float L = m + log2f(s) * LN2;   // row logsumexp
    float4 q0, q1;
    q0.x = exp2f((x0.x - L) * CQ);
    q0.y = exp2f((x0.y - L) * CQ);
    q0.z = exp2f((x0.z - L) * CQ);
    q0.w = exp2f((x0.w - L) * CQ);
    q1.x = exp2f((x1.x - L) * CQ);
    q1.y = exp2f((x1.y - L) * CQ);
    q1.z = exp2f((x1.z - L) * CQ);
    q1.w = exp2f((x1.w - L) * CQ);
    float4* qrow = reinterpret_cast<float4*>(qb + (size_t)r * KCOLS);
    qrow[lane]      = q0;   // cols 4l..4l+3
    qrow[64 + lane] = q1;   // cols 256+4l..256+4l+3
  }
  if (blockIdx.x == 0 && threadIdx.x < KP1)
    ws[OFF_B0 + threadIdx.x] = 1.0f / 513.0f;
}

// ---------------------------------------------------------------------------
// Kernel 2 (cooperative): the Sinkhorn while-loop on f32 Q (d_out scratch).
// Phase A (rows): fused a-update + column-partial accumulation, 4-row unroll
//                 with all 8 loads issued up front and 4 interleaved
//                 butterfly reductions (latency hiding on the ds pipe).
// Phase B (cols): reduce partials -> b update + per-column diff^2.
// err reduced with an identical fixed-order reduction in every block so the
// break decision is identical grid-wide.
// ---------------------------------------------------------------------------
__global__ __launch_bounds__(THREADS, 4) void sinkhorn_loop(
    const float* __restrict__ qb, float* __restrict__ ws) {
  float* a    = ws + OFF_A;
  float* b0   = ws + OFF_B0;
  float* b1   = ws + OFF_B1;
  float* bfin = ws + OFF_BF;
  float* ep   = ws + OFF_EP;
  float* colp = ws + OFF_CP;

  cg::grid_group grid = cg::this_grid();
  __shared__ float lds[WPB][KPAD];   // 16*520*4 = 33,280 B
  __shared__ float s_err;

  const int tid  = threadIdx.x;
  const int wv   = tid >> 6;
  const int lane = tid & 63;
  const int gw   = blockIdx.x * WPB + wv;   // global wave id [0, 4096)

  float err = 1.0f;
  int it = 0;
  for (; it < MAXIT; ++it) {
    if (!(err > STOPERR)) break;   // NaN err also stops (matches JAX)

    const float* bc = (it & 1) ? b1 : b0;
    float*       bn = (it & 1) ? b0 : b1;

    // stage current b: lane l holds b[4l..4l+3], b[256+4l..256+4l+3], b[512]
    const float4* bc4 = reinterpret_cast<const float4*>(bc);
    float4 rb0 = bc4[lane];
    float4 rb1 = bc4[64 + lane];
    float  bdum = bc[512];

    // ---- phase A: rows (4-row unroll) ----
    float cp[8] = {0.f, 0.f, 0.f, 0.f, 0.f, 0.f, 0.f, 0.f};
    float adum = 0.f;
    for (int r = gw; r < NROWS; r += 4 * NWAVES) {
      const int r1 = r + NWAVES, r2 = r + 2 * NWAVES, r3 = r + 3 * NWAVES;
      const float4* p0 = reinterpret_cast<const float4*>(qb + (size_t)r  * KCOLS);
      const float4* p1 = reinterpret_cast<const float4*>(qb + (size_t)r1 * KCOLS);
      const float4* p2 = reinterpret_cast<const float4*>(qb + (size_t)r2 * KCOLS);
      const float4* p3 = reinterpret_cast<const float4*>(qb + (size_t)r3 * KCOLS);
      float4 v0a = p0[lane],      v1a = p1[lane];
      float4 v2a = p2[lane],      v3a = p3[lane];
      float4 v0b = p0[64 + lane], v1b = p1[64 + lane];
      float4 v2b = p2[64 + lane], v3b = p3[64 + lane];
      float d0 = dot8(v0a, v0b, rb0, rb1);
      float d1 = dot8(v1a, v1b, rb0, rb1);
      float d2 = dot8(v2a, v2b, rb0, rb1);
      float d3 = dot8(v3a, v3b, rb0, rb1);
#pragma unroll
      for (int s = 32; s >= 1; s >>= 1) {   // 4 interleaved butterflies
        d0 += __shfl_xor(d0, s);
        d1 += __shfl_xor(d1, s);
        d2 += __shfl_xor(d2, s);
        d3 += __shfl_xor(d3, s);
      }
      float ai0 = PA / (d0 + bdum);
      float ai1 = PA / (d1 + bdum);
      float ai2 = PA / (d2 + bdum);
      float ai3 = PA / (d3 + bdum);
      if (lane == 0) { a[r] = ai0; a[r1] = ai1; a[r2] = ai2; a[r3] = ai3; }
      cpadd(v0a, v0b, ai0, cp);
      cpadd(v1a, v1b, ai1, cp);
      cpadd(v2a, v2b, ai2, cp);
      cpadd(v3a, v3b, ai3, cp);
      adum += (ai0 + ai1) + (ai2 + ai3);
    }
    // combine 16 waves' column partials via LDS -> one partial row per block
    {
      float4* dstA = reinterpret_cast<float4*>(&lds[wv][4 * lane]);
      float4* dstB = reinterpret_cast<float4*>(&lds[wv][256 + 4 * lane]);
      *dstA = make_float4(cp[0], cp[1], cp[2], cp[3]);
      *dstB = make_float4(cp[4], cp[5], cp[6], cp[7]);
      if (lane == 0) lds[wv][512] = adum;
    }
    __syncthreads();
    for (int t = tid; t < KP1; t += THREADS) {
      float s = 0.f;
#pragma unroll
      for (int w2 = 0; w2 < WPB; ++w2) s += lds[w2][t];
      colp[(size_t)blockIdx.x * KP1 + t] = s;
    }
    grid.sync();

    // ---- phase B: columns (waves 0..512, one column each) ----
    if (gw < KP1) {
      const int j = gw;
      float s = 0.f;
#pragma unroll
      for (int w2 = lane; w2 < BLOCKS; w2 += 64) s += colp[(size_t)w2 * KP1 + j];
      s = waveReduceSum(s);
      if (lane == 0) {
        float bj = (j < KCOLS) ? powf(PB_REAL / s, FI) : (PB_DUM / s);
        bn[j] = bj;
        float d = bj - bc[j];
        ep[j] = d * d;
      }
    }
    grid.sync();

    // ---- err: identical fixed-order reduction in every block ----
    if (wv == 0) {
      float s = 0.f;
      for (int t = lane; t < KP1; t += 64) s += ep[t];
      s = waveReduceSum(s);
      if (lane == 0) s_err = sqrtf(s);
    }
    __syncthreads();
    err = s_err;
  }

  // publish final b (bodies executed = it; last write went to buf[it&1])
  if (blockIdx.x == 0) {
    const float* bf = (it & 1) ? b1 : b0;
    for (int t = tid; t < KP1; t += THREADS) bfin[t] = bf[t];
  }
}

// ---------------------------------------------------------------------------
// Kernel 3: plan = n * a * Q * b^T, reading f32 Q from d_out and overwriting
// it in place with the plan (identical addresses per thread: read-then-write).
// ---------------------------------------------------------------------------
__global__ __launch_bounds__(1024) void plan_epilogue(
    const float* __restrict__ ws, float* __restrict__ out) {
  const float* a    = ws + OFF_A;
  const float* bfin = ws + OFF_BF;
  const int nw   = (gridDim.x * blockDim.x) >> 6;
  const int gw   = (blockIdx.x * blockDim.x + threadIdx.x) >> 6;
  const int lane = threadIdx.x & 63;

  const float4* b4 = reinterpret_cast<const float4*>(bfin);
  float4 rb0 = b4[lane];        // b[4l..4l+3]
  float4 rb1 = b4[64 + lane];   // b[256+4l..256+4l+3]

  for (int r = gw; r < NROWS; r += nw) {
    float4* row4 = reinterpret_cast<float4*>(out + (size_t)r * KCOLS);
    float na = a[r] * (float)NROWS;   // n * a_i
    float4 q0 = row4[lane];
    float4 q1 = row4[64 + lane];
    float4 o0, o1;
    o0.x = na * q0.x * rb0.x;
    o0.y = na * q0.y * rb0.y;
    o0.z = na * q0.z * rb0.z;
    o0.w = na * q0.w * rb0.w;
    o1.x = na * q1.x * rb1.x;
    o1.y = na * q1.y * rb1.y;
    o1.z = na * q1.z * rb1.z;
    o1.w = na * q1.w * rb1.w;
    row4[lane]      = o0;
    row4[64 + lane] = o1;
  }
}

extern "C" void kernel_launch(void* const* d_in, const int* in_sizes, int n_in,
                              void* d_out, int out_size, void* d_ws, size_t ws_size,
                              hipStream_t stream) {
  (void)in_sizes; (void)n_in; (void)out_size; (void)ws_size;
  const float* logits = (const float*)d_in[0];
  float*       out    = (float*)d_out;
  float*       ws     = (float*)d_ws;    // needs ~1.1 MB
  float*       qb     = (float*)d_out;   // f32 Q scratch (268 MB) in d_out

  hipLaunchKernelGGL(lse_q_init_kernel, dim3(1024), dim3(1024), 0, stream,
                     logits, ws, qb);

  const float* qArg  = qb;
  float*       wsArg = ws;
  void* args[] = { (void*)&qArg, (void*)&wsArg };
  hipLaunchCooperativeKernel((void*)sinkhorn_loop, dim3(BLOCKS), dim3(THREADS),
                             args, 0, stream);

  hipLaunchKernelGGL(plan_epilogue, dim3(2048), dim3(1024), 0, stream,
                     ws, out);
}

// Round 5
// 18168.631 us; speedup vs baseline: 2.2697x; 2.2697x over previous
//
#include <hip/hip_runtime.h>
#include <hip/hip_cooperative_groups.h>

// Problem constants (fixed by setup_inputs / reference)
constexpr int   NROWS   = 131072;
constexpr int   KCOLS   = 512;
constexpr int   KP1     = 513;   // + dummy column
constexpr float PA      = 1.0f / 131072.0f;
constexpr float PB_REAL = 0.5f / 512.0f;
constexpr float PB_DUM  = 0.5f;
constexpr float FI      = (float)(1.0 / 1.1); // GAMMA/(GAMMA+EPSILON)
constexpr float STOPERR = 1e-6f;
constexpr int   MAXIT   = 1000;
constexpr float LOG2E   = 1.4426950408889634f;
constexpr float CQ      = 10.0f * LOG2E;      // (1/EPSILON)*log2(e)
constexpr float LN2     = 0.6931471805599453f;

// Cooperative config: 256 blocks x 1024 threads -> guaranteed co-resident
// (1 block/CU min at VGPR<=128, LDS 33KB). Custom grid barrier, no cg::sync.
constexpr int BLOCKS  = 256;
constexpr int THREADS = 1024;
constexpr int WPB     = THREADS / 64;     // 16 waves per block
constexpr int NWAVES  = BLOCKS * WPB;     // 4096 waves
// NROWS / NWAVES = 32 rows per wave, in 8 groups of 4 (unroll)

// Workspace layout (floats). Total ~1.59 MB (proven ws_size >= 2.1 MB).
constexpr size_t OFF_LSE = 0;                        // [NROWS] row logsumexp
constexpr size_t OFF_A   = (size_t)NROWS;            // [NROWS] scaling a
constexpr int    KPAD    = 520;
constexpr size_t OFF_B0  = 2 * (size_t)NROWS;        // [KPAD]  b ping   (sc-only)
constexpr size_t OFF_B1  = OFF_B0 + KPAD;            // [KPAD]  b pong   (sc-only)
constexpr size_t OFF_BF  = OFF_B0 + 2 * KPAD;        // [KPAD]  b final  (normal)
constexpr size_t OFF_EP  = OFF_B0 + 3 * KPAD;        // [KPAD]  diff^2   (sc-only)
constexpr size_t OFF_CP  = OFF_B0 + 4 * KPAD;        // [KP1*BLOCKS] col partials, TRANSPOSED (sc-only)
constexpr size_t OFF_BAR = OFF_CP + (size_t)KP1 * BLOCKS;  // barrier cnt/gen (+64 pad)

// Q planes live in d_out: hi = ushort[NROWS*KCOLS] (134MB), lo = uchar[...] (67MB)
constexpr size_t QLO_BYTE_OFF = (size_t)NROWS * KCOLS * 2;

__device__ __forceinline__ float waveReduceSum(float v) {
#pragma unroll
  for (int s = 32; s >= 1; s >>= 1) v += __shfl_xor(v, s);
  return v;
}
__device__ __forceinline__ float waveReduceMax(float v) {
#pragma unroll
  for (int s = 32; s >= 1; s >>= 1) v = fmaxf(v, __shfl_xor(v, s));
  return v;
}

// device-coherent (agent-scope) accessors: bypass non-coherent L2, hit LLC.
__device__ __forceinline__ float scload(const float* p) {
  return __hip_atomic_load(p, __ATOMIC_RELAXED, __HIP_MEMORY_SCOPE_AGENT);
}
__device__ __forceinline__ void scstore(float* p, float v) {
  __hip_atomic_store(p, v, __ATOMIC_RELAXED, __HIP_MEMORY_SCOPE_AGENT);
}

// reconstruct 8 f32 Q values (24-bit: hi ushort + lo byte) from packed loads
__device__ __forceinline__ void unpack8(const uint4 h, const uint2 l, float q[8]) {
  q[0] = __uint_as_float((h.x << 16)         | ((l.x << 8) & 0xff00u));
  q[1] = __uint_as_float((h.x & 0xffff0000u) | ( l.x       & 0xff00u));
  q[2] = __uint_as_float((h.y << 16)         | ((l.x >> 8) & 0xff00u));
  q[3] = __uint_as_float((h.y & 0xffff0000u) | ((l.x >> 16)& 0xff00u));
  q[4] = __uint_as_float((h.z << 16)         | ((l.y << 8) & 0xff00u));
  q[5] = __uint_as_float((h.z & 0xffff0000u) | ( l.y       & 0xff00u));
  q[6] = __uint_as_float((h.w << 16)         | ((l.y >> 8) & 0xff00u));
  q[7] = __uint_as_float((h.w & 0xffff0000u) | ((l.y >> 16)& 0xff00u));
}

// ---------------------------------------------------------------------------
// Kernel 1: per-row logsumexp + 24-bit Q planes (into d_out) + loop-state init.
// One wave per row; lane l covers cols [4l..4l+3] and [256+4l..256+4l+3].
// ---------------------------------------------------------------------------
__global__ __launch_bounds__(1024) void lse_q_init_kernel(
    const float* __restrict__ logits, float* __restrict__ ws,
    unsigned short* __restrict__ qhi, unsigned char* __restrict__ qlo) {
  float* lse = ws + OFF_LSE;
  const int nw   = (gridDim.x * blockDim.x) >> 6;
  const int gw   = (blockIdx.x * blockDim.x + threadIdx.x) >> 6;
  const int lane = threadIdx.x & 63;

  for (int r = gw; r < NROWS; r += nw) {
    const float4* row4 = reinterpret_cast<const float4*>(logits + (size_t)r * KCOLS);
    float4 x0 = row4[lane];
    float4 x1 = row4[64 + lane];
    float m = fmaxf(fmaxf(fmaxf(x0.x, x0.y), fmaxf(x0.z, x0.w)),
                    fmaxf(fmaxf(x1.x, x1.y), fmaxf(x1.z, x1.w)));
    m = waveReduceMax(m);
    float s = exp2f((x0.x - m) * LOG2E) + exp2f((x0.y - m) * LOG2E)
            + exp2f((x0.z - m) * LOG2E) + exp2f((x0.w - m) * LOG2E)
            + exp2f((x1.x - m) * LOG2E) + exp2f((x1.y - m) * LOG2E)
            + exp2f((x1.z - m) * LOG2E) + exp2f((x1.w - m) * LOG2E);
    s = waveReduceSum(s);
    float L = m + log2f(s) * LN2;
    if (lane == 0) lse[r] = L;
    // Q = exp((x-L)/eps); pack rounded-to-24-bit f32 into hi/lo planes
    unsigned u[8];
    u[0] = __float_as_uint(exp2f((x0.x - L) * CQ)) + 0x80u;
    u[1] = __float_as_uint(exp2f((x0.y - L) * CQ)) + 0x80u;
    u[2] = __float_as_uint(exp2f((x0.z - L) * CQ)) + 0x80u;
    u[3] = __float_as_uint(exp2f((x0.w - L) * CQ)) + 0x80u;
    u[4] = __float_as_uint(exp2f((x1.x - L) * CQ)) + 0x80u;
    u[5] = __float_as_uint(exp2f((x1.y - L) * CQ)) + 0x80u;
    u[6] = __float_as_uint(exp2f((x1.z - L) * CQ)) + 0x80u;
    u[7] = __float_as_uint(exp2f((x1.w - L) * CQ)) + 0x80u;
    ushort4 hA, hB;  uchar4 lA, lB;
    hA.x = (unsigned short)(u[0] >> 16); lA.x = (unsigned char)(u[0] >> 8);
    hA.y = (unsigned short)(u[1] >> 16); lA.y = (unsigned char)(u[1] >> 8);
    hA.z = (unsigned short)(u[2] >> 16); lA.z = (unsigned char)(u[2] >> 8);
    hA.w = (unsigned short)(u[3] >> 16); lA.w = (unsigned char)(u[3] >> 8);
    hB.x = (unsigned short)(u[4] >> 16); lB.x = (unsigned char)(u[4] >> 8);
    hB.y = (unsigned short)(u[5] >> 16); lB.y = (unsigned char)(u[5] >> 8);
    hB.z = (unsigned short)(u[6] >> 16); lB.z = (unsigned char)(u[6] >> 8);
    hB.w = (unsigned short)(u[7] >> 16); lB.w = (unsigned char)(u[7] >> 8);
    *reinterpret_cast<ushort4*>(qhi + (size_t)r * KCOLS + 4 * lane)       = hA;
    *reinterpret_cast<ushort4*>(qhi + (size_t)r * KCOLS + 256 + 4 * lane) = hB;
    *reinterpret_cast<uchar4*>(qlo + (size_t)r * KCOLS + 4 * lane)        = lA;
    *reinterpret_cast<uchar4*>(qlo + (size_t)r * KCOLS + 256 + 4 * lane)  = lB;
  }
  if (blockIdx.x == 0 && threadIdx.x < KP1)
    ws[OFF_B0 + threadIdx.x] = 1.0f / 513.0f;
  if (blockIdx.x == 0 && threadIdx.x == 0) {
    ((unsigned*)(ws + OFF_BAR))[0] = 0u;   // arrival counter (cumulative)
    ((unsigned*)(ws + OFF_BAR + 32))[0] = 0u;  // generation
  }
}

// ---------------------------------------------------------------------------
// Kernel 2 (cooperative launch, custom barrier): the Sinkhorn while-loop on
// LLC-resident 24-bit Q. No fences / L2 flushes in the loop: all cross-block
// data goes through agent-scope (device-coherent) atomics; Q / lse / a use
// normal cached paths (Q is read-only; a is block-private until kernel end).
// ---------------------------------------------------------------------------
__global__ __launch_bounds__(THREADS, 4) void sinkhorn_loop(
    const unsigned short* __restrict__ qhi, const unsigned char* __restrict__ qlo,
    float* __restrict__ ws) {
  float* a    = ws + OFF_A;
  float* b0   = ws + OFF_B0;
  float* b1   = ws + OFF_B1;
  float* bfin = ws + OFF_BF;
  float* ep   = ws + OFF_EP;
  float* colp = ws + OFF_CP;
  unsigned* cnt = (unsigned*)(ws + OFF_BAR);
  unsigned* gen = (unsigned*)(ws + OFF_BAR + 32);

  __shared__ float lds[WPB][KPAD];   // 16*520*4 = 33,280 B
  __shared__ float s_err;
  __shared__ int   s_nbar;
  __shared__ int   s_dead;

  const int tid  = threadIdx.x;
  const int wv   = tid >> 6;
  const int lane = tid & 63;
  const int bk   = blockIdx.x;
  const int gw   = bk * WPB + wv;   // global wave id [0, 4096)

  if (tid == 0) { s_nbar = 0; s_dead = 0; }
  __syncthreads();

  // Grid barrier: __syncthreads drains each wave's vmem (compiler emits
  // s_waitcnt vmcnt(0) before s_barrier), so retired agent-scope stores are
  // LLC-visible before arrival. Generation counter is monotonic; expected
  // generation is derived locally (no racy pre-read of gen).
  auto gridBar = [&]() {
    __syncthreads();
    if (tid == 0) {
      int nb = s_nbar;
      unsigned old = atomicAdd(cnt, 1u);
      if (old == (unsigned)(nb * BLOCKS + (BLOCKS - 1))) {
        atomicAdd(gen, 1u);                    // release the generation
      } else if (!s_dead) {
        int spins = 0;
        while (__hip_atomic_load(gen, __ATOMIC_RELAXED, __HIP_MEMORY_SCOPE_AGENT)
               <= (unsigned)nb) {
          __builtin_amdgcn_s_sleep(1);
          if (++spins > (1 << 24)) { s_dead = 1; break; }  // fail-fast, no hang
        }
      }
      s_nbar = nb + 1;
    }
    __syncthreads();
  };

  float err = 1.0f;
  int it = 0;
  for (; it < MAXIT; ++it) {
    if (!(err > STOPERR)) break;   // NaN err also stops (matches JAX)

    const float* bcv = (it & 1) ? b1 : b0;
    float*       bnv = (it & 1) ? b0 : b1;

    // stage current b (written remotely last iter -> agent-scope loads)
    float rb[8];
#pragma unroll
    for (int e = 0; e < 8; ++e) rb[e] = scload(&bcv[8 * lane + e]);
    float bdum = scload(&bcv[512]);

    // ---- phase A: rows, 4-row unroll (normal cached loads of Q planes) ----
    float cp[8] = {0.f, 0.f, 0.f, 0.f, 0.f, 0.f, 0.f, 0.f};
    float adum = 0.f;
    for (int r = gw; r < NROWS; r += 4 * NWAVES) {
      const int r1 = r + NWAVES, r2 = r + 2 * NWAVES, r3 = r + 3 * NWAVES;
      uint4 h0 = ((const uint4*)(qhi + (size_t)r  * KCOLS))[lane];
      uint4 h1 = ((const uint4*)(qhi + (size_t)r1 * KCOLS))[lane];
      uint4 h2 = ((const uint4*)(qhi + (size_t)r2 * KCOLS))[lane];
      uint4 h3 = ((const uint4*)(qhi + (size_t)r3 * KCOLS))[lane];
      uint2 l0 = ((const uint2*)(qlo + (size_t)r  * KCOLS))[lane];
      uint2 l1 = ((const uint2*)(qlo + (size_t)r1 * KCOLS))[lane];
      uint2 l2 = ((const uint2*)(qlo + (size_t)r2 * KCOLS))[lane];
      uint2 l3 = ((const uint2*)(qlo + (size_t)r3 * KCOLS))[lane];
      float q0[8], q1[8], q2[8], q3[8];
      unpack8(h0, l0, q0);
      unpack8(h1, l1, q1);
      unpack8(h2, l2, q2);
      unpack8(h3, l3, q3);
      float d0 = 0.f, d1 = 0.f, d2 = 0.f, d3 = 0.f;
#pragma unroll
      for (int e = 0; e < 8; ++e) {
        d0 = fmaf(q0[e], rb[e], d0);
        d1 = fmaf(q1[e], rb[e], d1);
        d2 = fmaf(q2[e], rb[e], d2);
        d3 = fmaf(q3[e], rb[e], d3);
      }
#pragma unroll
      for (int s = 32; s >= 1; s >>= 1) {   // 4 interleaved butterflies
        d0 += __shfl_xor(d0, s);
        d1 += __shfl_xor(d1, s);
        d2 += __shfl_xor(d2, s);
        d3 += __shfl_xor(d3, s);
      }
      float ai0 = PA / (d0 + bdum);
      float ai1 = PA / (d1 + bdum);
      float ai2 = PA / (d2 + bdum);
      float ai3 = PA / (d3 + bdum);
      if (lane == 0) { a[r] = ai0; a[r1] = ai1; a[r2] = ai2; a[r3] = ai3; }
#pragma unroll
      for (int e = 0; e < 8; ++e) {
        cp[e] = fmaf(ai0, q0[e], cp[e]);
        cp[e] = fmaf(ai1, q1[e], cp[e]);
        cp[e] = fmaf(ai2, q2[e], cp[e]);
        cp[e] = fmaf(ai3, q3[e], cp[e]);
      }
      adum += (ai0 + ai1) + (ai2 + ai3);
    }
    // combine 16 waves' partials in LDS -> transposed colp (agent-scope)
#pragma unroll
    for (int e = 0; e < 8; ++e) lds[wv][8 * lane + e] = cp[e];
    if (lane == 0) lds[wv][512] = adum;
    __syncthreads();
    for (int t = tid; t < KP1; t += THREADS) {
      float s = 0.f;
#pragma unroll
      for (int w2 = 0; w2 < WPB; ++w2) s += lds[w2][t];
      scstore(&colp[(size_t)t * BLOCKS + bk], s);
    }
    gridBar();

    // ---- phase B: columns, distributed over all blocks (2 cols each) ----
    {
      int jcol = (wv == 0) ? 2 * bk
               : (wv == 1) ? 2 * bk + 1
               : (bk == 0 && wv == 2) ? 512 : -1;
      if (jcol >= 0) {
        float s = 0.f;
#pragma unroll
        for (int e = 0; e < 4; ++e)
          s += scload(&colp[(size_t)jcol * BLOCKS + 4 * lane + e]);
        s = waveReduceSum(s);
        if (lane == 0) {
          float bj = (jcol < KCOLS) ? powf(PB_REAL / s, FI) : (PB_DUM / s);
          scstore(&bnv[jcol], bj);
          float d = bj - scload(&bcv[jcol]);
          scstore(&ep[jcol], d * d);
        }
      }
    }
    gridBar();

    // ---- err: identical fixed-order reduction in every block ----
    if (wv == 0) {
      float s = 0.f;
      for (int t = lane; t < KP1; t += 64) s += scload(&ep[t]);
      s = waveReduceSum(s);
      if (lane == 0) s_err = sqrtf(s);
    }
    __syncthreads();
    err = s_err;
  }

  // publish final b for the epilogue (bodies executed = it)
  if (bk == 0) {
    const float* bf = (it & 1) ? b1 : b0;
    for (int t = tid; t < KP1; t += THREADS) bfin[t] = scload(&bf[t]);
  }
}

// ---------------------------------------------------------------------------
// Kernel 3: plan = n * a * Q * b^T, recomputing Q in f32 from logits+lse
// (d_out, which held the Q planes, is overwritten with the plan; this kernel
// reads only logits/ws, so no in-place hazard).
// ---------------------------------------------------------------------------
__global__ __launch_bounds__(1024) void plan_epilogue(
    const float* __restrict__ logits, const float* __restrict__ ws,
    float* __restrict__ out) {
  const float* lse  = ws + OFF_LSE;
  const float* a    = ws + OFF_A;
  const float* bfin = ws + OFF_BF;
  const int nw   = (gridDim.x * blockDim.x) >> 6;
  const int gw   = (blockIdx.x * blockDim.x + threadIdx.x) >> 6;
  const int lane = threadIdx.x & 63;

  const float4* b4 = reinterpret_cast<const float4*>(bfin);
  float4 rb0 = b4[lane];        // b[4l..4l+3]
  float4 rb1 = b4[64 + lane];   // b[256+4l..256+4l+3]

  for (int r = gw; r < NROWS; r += nw) {
    const float4* row4 = reinterpret_cast<const float4*>(logits + (size_t)r * KCOLS);
    float4*       out4 = reinterpret_cast<float4*>(out + (size_t)r * KCOLS);
    float L  = lse[r];
    float na = a[r] * (float)NROWS;   // n * a_i
    float4 x0 = row4[lane];
    float4 x1 = row4[64 + lane];
    float4 o0, o1;
    o0.x = na * exp2f((x0.x - L) * CQ) * rb0.x;
    o0.y = na * exp2f((x0.y - L) * CQ) * rb0.y;
    o0.z = na * exp2f((x0.z - L) * CQ) * rb0.z;
    o0.w = na * exp2f((x0.w - L) * CQ) * rb0.w;
    o1.x = na * exp2f((x1.x - L) * CQ) * rb1.x;
    o1.y = na * exp2f((x1.y - L) * CQ) * rb1.y;
    o1.z = na * exp2f((x1.z - L) * CQ) * rb1.z;
    o1.w = na * exp2f((x1.w - L) * CQ) * rb1.w;
    out4[lane]      = o0;
    out4[64 + lane] = o1;
  }
}

extern "C" void kernel_launch(void* const* d_in, const int* in_sizes, int n_in,
                              void* d_out, int out_size, void* d_ws, size_t ws_size,
                              hipStream_t stream) {
  (void)in_sizes; (void)n_in; (void)out_size; (void)ws_size;
  const float*    logits = (const float*)d_in[0];
  float*          out    = (float*)d_out;
  float*          ws     = (float*)d_ws;    // needs ~1.6 MB
  unsigned short* qhi    = (unsigned short*)d_out;                        // 134 MB
  unsigned char*  qlo    = (unsigned char*)d_out + QLO_BYTE_OFF;          // 67 MB

  hipLaunchKernelGGL(lse_q_init_kernel, dim3(1024), dim3(1024), 0, stream,
                     logits, ws, qhi, qlo);

  const unsigned short* qhArg = qhi;
  const unsigned char*  qlArg = qlo;
  float*                wsArg = ws;
  void* args[] = { (void*)&qhArg, (void*)&qlArg, (void*)&wsArg };
  hipLaunchCooperativeKernel((void*)sinkhorn_loop, dim3(BLOCKS), dim3(THREADS),
                             args, 0, stream);

  hipLaunchKernelGGL(plan_epilogue, dim3(2048), dim3(1024), 0, stream,
                     logits, ws, out);
}